// Round 3
// baseline (514.359 us; speedup 1.0000x reference)
//
#include <hip/hip_runtime.h>
#include <cstddef>

namespace nl {
constexpr int B = 2, C = 3, H = 63, W = 63, K = 7;
constexpr int NH = 57, NW = 57, N = NH * NW;      // 3249
constexpr int KS = 147, KSP = 160, NPAD = 3328;   // Xr rows / row stride
constexpr int KSP2 = 192;                          // Xi rows padded for gemm2 tiling
constexpr int MTOT = 3264;                         // m-loop bound (>=N, 17*192)
constexpr int SPLITS = 17;
constexpr int MCHUNK = MTOT / SPLITS;              // 192
constexpr int NT = 128;                            // gemm2 n-tile

constexpr size_t SZ_XR  = (size_t)B * KSP * NPAD;   // 1,064,960
constexpr size_t SZ_XI  = (size_t)B * KSP2 * NPAD;  // 1,277,952
constexpr size_t OFF_XR = 0;
constexpr size_t OFF_XI = OFF_XR + SZ_XR;
constexpr size_t OFF_SQ = OFF_XI + SZ_XI;
constexpr size_t OFF_HD = OFF_SQ + (size_t)B * NPAD;
constexpr size_t OFF_BLK = OFF_HD + (size_t)B * NPAD;
constexpr size_t OFF_D  = OFF_BLK + (size_t)B * NPAD;
constexpr size_t OFF_BIMG = OFF_D + (size_t)B * NPAD;
constexpr size_t OFF_ATT = OFF_BIMG + 8192;
constexpr size_t SZ_ATT = (size_t)B * NPAD * NPAD;
constexpr size_t OFF_OUTA = OFF_ATT + SZ_ATT;       // [B][KSP2][NPAD] atomic accum
// total = OFF_OUTA + SZ_XI ~ 98.4 MiB
}
using namespace nl;

// ---------------- block detect (sobel + angle test) ----------------
__global__ __launch_bounds__(256) void nl_block(const float* __restrict__ x,
                                                const float* __restrict__ y,
                                                float* __restrict__ bimg) {
  int idx = blockIdx.x * 256 + threadIdx.x;
  if (idx >= B * H * W) return;
  int q = idx % W, t = idx / W;
  int p = t % H, b = t / H;
  float gx[3][3], gy[3][3];
#pragma unroll
  for (int dy = 0; dy < 3; ++dy)
#pragma unroll
    for (int dx = 0; dx < 3; ++dx) {
      int pp = p + dy - 1, qq = q + dx - 1;
      float vx = 0.f, vy = 0.f;
      if (pp >= 0 && pp < H && qq >= 0 && qq < W) {
        int base = (b * C * H + pp) * W + qq;
        vx = 0.299f * x[base] + 0.587f * x[base + H * W] + 0.114f * x[base + 2 * H * W];
        vy = 0.299f * y[base] + 0.587f * y[base + H * W] + 0.114f * y[base + 2 * H * W];
      }
      gx[dy][dx] = vx; gy[dy][dx] = vy;
    }
  float in_gx = (q == W - 1) ? 1.f : (-gx[0][0] + gx[0][2] - 2.f * gx[1][0] + 2.f * gx[1][2] - gx[2][0] + gx[2][2]);
  float in_gy = (p == H - 1) ? 1.f : (-gx[0][0] - 2.f * gx[0][1] - gx[0][2] + gx[2][0] + 2.f * gx[2][1] + gx[2][2]);
  float rf_gx = (q == W - 1) ? 1.f : (-gy[0][0] + gy[0][2] - 2.f * gy[1][0] + 2.f * gy[1][2] - gy[2][0] + gy[2][2]);
  float rf_gy = (p == H - 1) ? 1.f : (-gy[0][0] - 2.f * gy[0][1] - gy[0][2] + gy[2][0] + 2.f * gy[2][1] + gy[2][2]);
  float n_in = sqrtf(in_gx * in_gx + in_gy * in_gy);
  float n_rf = sqrtf(rf_gx * rf_gx + rf_gy * rf_gy);
  float cosv = (in_gx * rf_gx + in_gy * rf_gy + 0.001f) / (n_in * n_rf + 0.001f);
  float det = (n_in >= 29.f) ? ((n_rf >= 29.f) ? (1.f - cosv) : 1.f) : 0.f;
  bimg[(b * H + p) * W + q] = 1.f - det;
}

// ---------------- blk_p: 7x7 box mean of block image ----------------
__global__ __launch_bounds__(256) void nl_blkp(const float* __restrict__ bimg,
                                               float* __restrict__ blk) {
  int idx = blockIdx.x * 256 + threadIdx.x;
  if (idx >= B * NPAD) return;
  int n = idx % NPAD, b = idx / NPAD;
  float v = 0.f;
  if (n < N) {
    int i = n / NW, j = n % NW;
    float s = 0.f;
#pragma unroll
    for (int ky = 0; ky < K; ++ky)
#pragma unroll
      for (int kx = 0; kx < K; ++kx)
        s += bimg[(b * H + i + ky) * W + (j + kx)];
    v = s * (1.f / 49.f);
  }
  blk[idx] = v;
}

// ---------------- im2col: Xr [B][160][NPAD] from y, Xi [B][192][NPAD] from x ----------------
__global__ __launch_bounds__(256) void nl_im2col(const float* __restrict__ x,
                                                 const float* __restrict__ y,
                                                 float* __restrict__ ws) {
  size_t idx = (size_t)blockIdx.x * 256 + threadIdx.x;
  size_t tot = SZ_XR + SZ_XI;
  if (idx >= tot) return;
  if (idx < SZ_XR) {
    int n = (int)(idx % NPAD);
    int r1 = (int)(idx / NPAD);
    int k = r1 % KSP, b = r1 / KSP;
    float v = 0.f;
    if (k < KS && n < N) {
      int c = k / 49, r = k % 49;
      int ky = r / 7, kx = r % 7;
      int i = n / NW, j = n % NW;
      v = y[((b * C + c) * H + (i + ky)) * W + (j + kx)];
    }
    ws[OFF_XR + idx] = v;
  } else {
    size_t idx2 = idx - SZ_XR;
    int n = (int)(idx2 % NPAD);
    int r1 = (int)(idx2 / NPAD);
    int k = r1 % KSP2, b = r1 / KSP2;
    float v = 0.f;
    if (k < KS && n < N) {
      int c = k / 49, r = k % 49;
      int ky = r / 7, kx = r % 7;
      int i = n / NW, j = n % NW;
      v = x[((b * C + c) * H + (i + ky)) * W + (j + kx)];
    }
    ws[OFF_XI + idx2] = v;
  }
}

// ---------------- per-query sq, h-network; init Dv=1 ----------------
__global__ __launch_bounds__(256) void nl_sqh(const float* __restrict__ ws_xr,
                                              const float* __restrict__ w1,
                                              const float* __restrict__ b1,
                                              const float* __restrict__ w2,
                                              const float* __restrict__ b2,
                                              float* __restrict__ sq,
                                              float* __restrict__ hd,
                                              float* __restrict__ Dv) {
  int idx = blockIdx.x * 256 + threadIdx.x;
  if (idx >= B * NPAD) return;
  int n = idx % NPAD, b = idx / NPAD;
  Dv[idx] = 1.f;  // overwritten for n<N by softmax; keeps junk columns finite
  if (n >= N) { sq[idx] = 0.f; hd[idx] = 1.f; return; }
  const float* Xr = ws_xr + (size_t)b * KSP * NPAD + n;
  float s = 0.f, h0 = b1[0], h1 = b1[1], h2 = b1[2];
  for (int k = 0; k < KS; ++k) {
    float v = Xr[(size_t)k * NPAD];
    s += v * v;
    h0 += v * w1[k];
    h1 += v * w1[KS + k];
    h2 += v * w1[2 * KS + k];
  }
  h0 = fmaxf(h0, 0.f); h1 = fmaxf(h1, 0.f); h2 = fmaxf(h2, 0.f);
  float h = h0 * w2[0] + h1 * w2[1] + h2 * w2[2] + b2[0];
  sq[idx] = s;
  hd[idx] = h * h + 1.f;
}

// ---------------- GEMM1 (symmetric-half): att = (2*XY - sq_n - sq_m) / hd_n ----------------
__global__ __launch_bounds__(256) void nl_gemm1(const float* __restrict__ ws_xr,
                                                const float* __restrict__ sq,
                                                const float* __restrict__ hd,
                                                float* __restrict__ att) {
  int bx = blockIdx.x, by = blockIdx.y;
  if (bx < by) return;  // upper triangle incl. diagonal; mirror writes lower
  __shared__ float As[32][128];
  __shared__ float Bs[32][128];
  int b = blockIdx.z;
  const float* Xb = ws_xr + (size_t)b * KSP * NPAD;
  int row0 = by * 128, col0 = bx * 128;
  int t = threadIdx.x;
  int tr = t >> 4, tc = t & 15;
  float acc[8][8];
#pragma unroll
  for (int i = 0; i < 8; ++i)
#pragma unroll
    for (int j = 0; j < 8; ++j) acc[i][j] = 0.f;

  for (int kt = 0; kt < KSP; kt += 32) {
#pragma unroll
    for (int u = 0; u < 4; ++u) {
      int e = t + u * 256;
      int kk = e >> 5, cc = e & 31;
      float4 va = *(const float4*)(Xb + (size_t)(kt + kk) * NPAD + row0 + cc * 4);
      *(float4*)(&As[kk][cc * 4]) = va;
      float4 vb = *(const float4*)(Xb + (size_t)(kt + kk) * NPAD + col0 + cc * 4);
      *(float4*)(&Bs[kk][cc * 4]) = vb;
    }
    __syncthreads();
#pragma unroll
    for (int kk = 0; kk < 32; ++kk) {
      float a[8], bb[8];
      *(float4*)(&a[0]) = *(const float4*)(&As[kk][tr * 4]);
      *(float4*)(&a[4]) = *(const float4*)(&As[kk][64 + tr * 4]);
      *(float4*)(&bb[0]) = *(const float4*)(&Bs[kk][tc * 4]);
      *(float4*)(&bb[4]) = *(const float4*)(&Bs[kk][64 + tc * 4]);
#pragma unroll
      for (int i = 0; i < 8; ++i)
#pragma unroll
        for (int j = 0; j < 8; ++j) acc[i][j] = fmaf(a[i], bb[j], acc[i][j]);
    }
    __syncthreads();
  }
  int rI[8], cJ[8];
#pragma unroll
  for (int i = 0; i < 4; ++i) { rI[i] = row0 + tr * 4 + i; rI[i + 4] = row0 + 64 + tr * 4 + i; }
#pragma unroll
  for (int j = 0; j < 4; ++j) { cJ[j] = col0 + tc * 4 + j; cJ[j + 4] = col0 + 64 + tc * 4 + j; }
  float sqn[8], hdn[8], sqm[8], hdm[8];
#pragma unroll
  for (int i = 0; i < 8; ++i) { sqn[i] = sq[b * NPAD + rI[i]]; hdn[i] = hd[b * NPAD + rI[i]]; }
#pragma unroll
  for (int j = 0; j < 8; ++j) { sqm[j] = sq[b * NPAD + cJ[j]]; hdm[j] = hd[b * NPAD + cJ[j]]; }
  // direct tile
#pragma unroll
  for (int i = 0; i < 8; ++i) {
    float v[8];
    float inv = 1.f / hdn[i];
#pragma unroll
    for (int j = 0; j < 8; ++j) v[j] = (2.f * acc[i][j] - sqn[i] - sqm[j]) * inv;
    float* arow = att + ((size_t)b * NPAD + rI[i]) * NPAD;
    *(float4*)(arow + col0 + tc * 4) = *(float4*)(&v[0]);
    *(float4*)(arow + col0 + 64 + tc * 4) = *(float4*)(&v[4]);
  }
  if (bx != by) {  // mirrored tile (lower triangle), row-epilogue of row cJ[j]
#pragma unroll
    for (int j = 0; j < 8; ++j) {
      float v[8];
      float inv = 1.f / hdm[j];
#pragma unroll
      for (int i = 0; i < 8; ++i) v[i] = (2.f * acc[i][j] - sqm[j] - sqn[i]) * inv;
      float* arow = att + ((size_t)b * NPAD + cJ[j]) * NPAD;
      *(float4*)(arow + row0 + tr * 4) = *(float4*)(&v[0]);
      *(float4*)(arow + row0 + 64 + tr * 4) = *(float4*)(&v[4]);
    }
  }
}

// ---------------- softmax rows: store e*blk, denominators to D ----------------
__global__ __launch_bounds__(256) void nl_softmax(float* __restrict__ att,
                                                  const float* __restrict__ blk,
                                                  float* __restrict__ Dv) {
  int n = blockIdx.x, b = blockIdx.y;
  int tid = threadIdx.x;
  float* row = att + ((size_t)b * NPAD + n) * NPAD;
  __shared__ float red[256];
  float lmax = -1e30f;
  for (int m = tid; m < N; m += 256) lmax = fmaxf(lmax, row[m]);
  red[tid] = lmax;
  __syncthreads();
  for (int s = 128; s > 0; s >>= 1) {
    if (tid < s) red[tid] = fmaxf(red[tid], red[tid + s]);
    __syncthreads();
  }
  float mx = red[0];
  __syncthreads();
  const float* bl = blk + b * NPAD;
  float s1 = 0.f, s2 = 0.f;
  for (int m = tid; m < N; m += 256) {
    float e = __expf(row[m] - mx);
    float eb = e * bl[m];
    row[m] = eb;
    s1 += e;
    s2 += eb;
  }
  for (int m = N + tid; m < NPAD; m += 256) row[m] = 0.f;  // zero pad cols
  red[tid] = s1;
  __syncthreads();
  for (int s = 128; s > 0; s >>= 1) {
    if (tid < s) red[tid] += red[tid + s];
    __syncthreads();
  }
  float s1t = red[0];
  __syncthreads();
  red[tid] = s2;
  __syncthreads();
  for (int s = 128; s > 0; s >>= 1) {
    if (tid < s) red[tid] += red[tid + s];
    __syncthreads();
  }
  if (tid == 0) Dv[b * NPAD + n] = red[0] + 0.001f * s1t;
}

// ---------------- GEMM2: out[k,n] += att[n,m]*Xi[k,m] / D[n]; 128n x 192k tile, split-K=17 ----------------
__global__ __launch_bounds__(256) void nl_gemm2(const float* __restrict__ att,
                                                const float* __restrict__ ws_xi,
                                                const float* __restrict__ Dv,
                                                float* __restrict__ outp0) {
  __shared__ float Ps[32][132];   // [m][n] transposed; stride 132 (16B-aligned rows)
  __shared__ float Xs[32][196];   // [m][k] transposed; stride 196
  int b = blockIdx.z;
  int n0 = blockIdx.x * NT;
  int m0 = blockIdx.y * MCHUNK;
  const float* attb = att + (size_t)b * NPAD * NPAD;
  const float* Xib = ws_xi + (size_t)b * KSP2 * NPAD;
  int t = threadIdx.x;
  int tn = t & 15, tk = t >> 4;
  float acc[8][12];
#pragma unroll
  for (int i = 0; i < 8; ++i)
#pragma unroll
    for (int j = 0; j < 12; ++j) acc[i][j] = 0.f;

  for (int mt = m0; mt < m0 + MCHUNK; mt += 32) {
#pragma unroll
    for (int u = 0; u < 4; ++u) {  // att tile 128n x 32m -> Ps[m][n]
      int e = t + u * 256;
      int r = e >> 3, c = e & 7;
      float4 v = *(const float4*)(attb + (size_t)(n0 + r) * NPAD + mt + c * 4);
      Ps[c * 4 + 0][r] = v.x; Ps[c * 4 + 1][r] = v.y;
      Ps[c * 4 + 2][r] = v.z; Ps[c * 4 + 3][r] = v.w;
    }
#pragma unroll
    for (int u = 0; u < 6; ++u) {  // Xi tile 192k x 32m -> Xs[m][k]
      int e = t + u * 256;
      int r = e >> 3, c = e & 7;
      float4 v = *(const float4*)(Xib + (size_t)r * NPAD + mt + c * 4);
      Xs[c * 4 + 0][r] = v.x; Xs[c * 4 + 1][r] = v.y;
      Xs[c * 4 + 2][r] = v.z; Xs[c * 4 + 3][r] = v.w;
    }
    __syncthreads();
#pragma unroll
    for (int mm = 0; mm < 32; ++mm) {
      float a[8], bb[12];
      *(float4*)(&a[0]) = *(const float4*)(&Ps[mm][tn * 4]);
      *(float4*)(&a[4]) = *(const float4*)(&Ps[mm][64 + tn * 4]);
      *(float4*)(&bb[0]) = *(const float4*)(&Xs[mm][tk * 4]);
      *(float4*)(&bb[4]) = *(const float4*)(&Xs[mm][64 + tk * 4]);
      *(float4*)(&bb[8]) = *(const float4*)(&Xs[mm][128 + tk * 4]);
#pragma unroll
      for (int i = 0; i < 8; ++i)
#pragma unroll
        for (int j = 0; j < 12; ++j) acc[i][j] = fmaf(a[i], bb[j], acc[i][j]);
    }
    __syncthreads();
  }
  float* outp = outp0 + (size_t)b * KSP2 * NPAD;
#pragma unroll
  for (int i = 0; i < 8; ++i) {
    int n = n0 + ((i < 4) ? (tn * 4 + i) : (64 + tn * 4 + i - 4));
    float dinv = 1.0f / Dv[b * NPAD + n];
#pragma unroll
    for (int j = 0; j < 12; ++j) {
      int k = (j < 4) ? (tk * 4 + j) : ((j < 8) ? (64 + tk * 4 + j - 4) : (128 + tk * 4 + j - 8));
      atomicAdd(outp + (size_t)k * NPAD + n, acc[i][j] * dinv);
    }
  }
}

// ---------------- fold (overlap-add adjoint of im2col) + weight divide ----------------
__global__ __launch_bounds__(256) void nl_fold(const float* __restrict__ outA,
                                               float* __restrict__ out) {
  int idx = blockIdx.x * 256 + threadIdx.x;
  if (idx >= B * C * H * W) return;
  int q = idx % W, t = idx / W;
  int p = t % H, t2 = t / H;
  int c = t2 % C, b = t2 / C;
  float s = 0.f;
#pragma unroll
  for (int ky = 0; ky < K; ++ky) {
    int iy = p - ky;
    if (iy < 0 || iy >= NH) continue;
#pragma unroll
    for (int kx = 0; kx < K; ++kx) {
      int jx = q - kx;
      if (jx < 0 || jx >= NW) continue;
      size_t o = ((size_t)(b * KSP2 + c * 49 + ky * 7 + kx)) * NPAD + iy * NW + jx;
      s += outA[o];
    }
  }
  int cy = min(p, 6) - max(0, p - 56) + 1;
  int cx = min(q, 6) - max(0, q - 56) + 1;
  out[idx] = s / (float)(cy * cx);
}

extern "C" void kernel_launch(void* const* d_in, const int* in_sizes, int n_in,
                              void* d_out, int out_size, void* d_ws, size_t ws_size,
                              hipStream_t stream) {
  const float* x = (const float*)d_in[0];
  const float* y = (const float*)d_in[1];
  const float* w1 = (const float*)d_in[2];
  const float* b1 = (const float*)d_in[3];
  const float* w2 = (const float*)d_in[4];
  const float* b2 = (const float*)d_in[5];
  float* ws = (float*)d_ws;
  float* out = (float*)d_out;

  float* Xr = ws + OFF_XR;
  float* Xi = ws + OFF_XI;
  float* sq = ws + OFF_SQ;
  float* hd = ws + OFF_HD;
  float* blk = ws + OFF_BLK;
  float* Dv = ws + OFF_D;
  float* bimg = ws + OFF_BIMG;
  float* att = ws + OFF_ATT;
  float* outA = ws + OFF_OUTA;

  hipMemsetAsync(outA, 0, SZ_XI * sizeof(float), stream);

  nl_block<<<(B * H * W + 255) / 256, 256, 0, stream>>>(x, y, bimg);
  nl_im2col<<<(int)((SZ_XR + SZ_XI + 255) / 256), 256, 0, stream>>>(x, y, ws);
  nl_blkp<<<(B * NPAD + 255) / 256, 256, 0, stream>>>(bimg, blk);
  nl_sqh<<<(B * NPAD + 255) / 256, 256, 0, stream>>>(Xr, w1, b1, w2, b2, sq, hd, Dv);
  nl_gemm1<<<dim3(NPAD / 128, NPAD / 128, B), 256, 0, stream>>>(Xr, sq, hd, att);
  nl_softmax<<<dim3(N, B), 256, 0, stream>>>(att, blk, Dv);
  nl_gemm2<<<dim3(NPAD / NT, SPLITS, B), 256, 0, stream>>>(att, Xi, Dv, outA);
  nl_fold<<<(B * C * H * W + 255) / 256, 256, 0, stream>>>(outA, out);
}

// Round 4
// 378.891 us; speedup vs baseline: 1.3575x; 1.3575x over previous
//
#include <hip/hip_runtime.h>
#include <cstddef>

namespace nl {
constexpr int B = 2, C = 3, H = 63, W = 63, K = 7;
constexpr int NH = 57, NW = 57, N = NH * NW;      // 3249
constexpr int KS = 147, KSP = 160, NPAD = 3328;
constexpr int SPLITS = 13;
constexpr int MCHUNK = NPAD / SPLITS;             // 256
constexpr size_t SZ_X   = (size_t)B * KSP * NPAD; // 1,064,960 floats
constexpr size_t OFF_XR = 0;                      // ref patches (from y)
constexpr size_t OFF_XI = OFF_XR + SZ_X;          // inp patches (from x)
constexpr size_t OFF_SQ = OFF_XI + SZ_X;
constexpr size_t OFF_HD = OFF_SQ + (size_t)B * NPAD;
constexpr size_t OFF_BLK = OFF_HD + (size_t)B * NPAD;
constexpr size_t OFF_D  = OFF_BLK + (size_t)B * NPAD;  // Dinv (1/denominator)
constexpr size_t OFF_MX = OFF_D + (size_t)B * NPAD;    // row max
constexpr size_t OFF_BIMG = OFF_MX + (size_t)B * NPAD;
constexpr size_t OFF_ATT = OFF_BIMG + 8192;            // raw scores [B][NPAD][NPAD]
constexpr size_t SZ_ATT = (size_t)B * NPAD * NPAD;
constexpr size_t OFF_OUTA = OFF_ATT + SZ_ATT;          // atomic accum [B][KSP][NPAD]
// total = OFF_OUTA + SZ_X ~ 97 MiB
}
using namespace nl;

// ---------------- block detect (sobel + angle test) ----------------
__global__ __launch_bounds__(256) void nl_block(const float* __restrict__ x,
                                                const float* __restrict__ y,
                                                float* __restrict__ bimg) {
  int idx = blockIdx.x * 256 + threadIdx.x;
  if (idx >= B * H * W) return;
  int q = idx % W, t = idx / W;
  int p = t % H, b = t / H;
  float gx[3][3], gy[3][3];
#pragma unroll
  for (int dy = 0; dy < 3; ++dy)
#pragma unroll
    for (int dx = 0; dx < 3; ++dx) {
      int pp = p + dy - 1, qq = q + dx - 1;
      float vx = 0.f, vy = 0.f;
      if (pp >= 0 && pp < H && qq >= 0 && qq < W) {
        int base = (b * C * H + pp) * W + qq;
        vx = 0.299f * x[base] + 0.587f * x[base + H * W] + 0.114f * x[base + 2 * H * W];
        vy = 0.299f * y[base] + 0.587f * y[base + H * W] + 0.114f * y[base + 2 * H * W];
      }
      gx[dy][dx] = vx; gy[dy][dx] = vy;
    }
  float in_gx = (q == W - 1) ? 1.f : (-gx[0][0] + gx[0][2] - 2.f * gx[1][0] + 2.f * gx[1][2] - gx[2][0] + gx[2][2]);
  float in_gy = (p == H - 1) ? 1.f : (-gx[0][0] - 2.f * gx[0][1] - gx[0][2] + gx[2][0] + 2.f * gx[2][1] + gx[2][2]);
  float rf_gx = (q == W - 1) ? 1.f : (-gy[0][0] + gy[0][2] - 2.f * gy[1][0] + 2.f * gy[1][2] - gy[2][0] + gy[2][2]);
  float rf_gy = (p == H - 1) ? 1.f : (-gy[0][0] - 2.f * gy[0][1] - gy[0][2] + gy[2][0] + 2.f * gy[2][1] + gy[2][2]);
  float n_in = sqrtf(in_gx * in_gx + in_gy * in_gy);
  float n_rf = sqrtf(rf_gx * rf_gx + rf_gy * rf_gy);
  float cosv = (in_gx * rf_gx + in_gy * rf_gy + 0.001f) / (n_in * n_rf + 0.001f);
  float det = (n_in >= 29.f) ? ((n_rf >= 29.f) ? (1.f - cosv) : 1.f) : 0.f;
  bimg[(b * H + p) * W + q] = 1.f - det;
}

// ---------------- blk_p: 7x7 box mean of block image (0 for n>=N) ----------------
__global__ __launch_bounds__(256) void nl_blkp(const float* __restrict__ bimg,
                                               float* __restrict__ blk) {
  int idx = blockIdx.x * 256 + threadIdx.x;
  if (idx >= B * NPAD) return;
  int n = idx % NPAD, b = idx / NPAD;
  float v = 0.f;
  if (n < N) {
    int i = n / NW, j = n % NW;
    float s = 0.f;
#pragma unroll
    for (int ky = 0; ky < K; ++ky)
#pragma unroll
      for (int kx = 0; kx < K; ++kx)
        s += bimg[(b * H + i + ky) * W + (j + kx)];
    v = s * (1.f / 49.f);
  }
  blk[idx] = v;
}

// ---------------- im2col: Xr (from y) and Xi (from x), [B][160][NPAD] zero-padded ----------------
__global__ __launch_bounds__(256) void nl_im2col(const float* __restrict__ x,
                                                 const float* __restrict__ y,
                                                 float* __restrict__ ws) {
  int idx = blockIdx.x * 256 + threadIdx.x;
  if (idx >= (int)(2 * SZ_X)) return;
  int n = idx % NPAD;
  int r1 = idx / NPAD;
  int k = r1 % KSP;
  int r2 = r1 / KSP;
  int b = r2 % B;
  int which = r2 / B;  // 0 -> Xr (from y), 1 -> Xi (from x)
  float v = 0.f;
  if (k < KS && n < N) {
    int c = k / 49, r = k % 49;
    int ky = r / 7, kx = r % 7;
    int i = n / NW, j = n % NW;
    const float* src = which ? x : y;
    v = src[((b * C + c) * H + (i + ky)) * W + (j + kx)];
  }
  ws[OFF_XR + idx] = v;
}

// ---------------- per-query sq, h-network; init Dinv=1, mx=0 ----------------
__global__ __launch_bounds__(256) void nl_sqh(const float* __restrict__ ws_xr,
                                              const float* __restrict__ w1,
                                              const float* __restrict__ b1,
                                              const float* __restrict__ w2,
                                              const float* __restrict__ b2,
                                              float* __restrict__ sq,
                                              float* __restrict__ hd,
                                              float* __restrict__ dinv,
                                              float* __restrict__ mx) {
  int idx = blockIdx.x * 256 + threadIdx.x;
  if (idx >= B * NPAD) return;
  int n = idx % NPAD, b = idx / NPAD;
  dinv[idx] = 1.f;  // overwritten for n<N by softmax; keeps junk rows finite
  mx[idx] = 0.f;
  if (n >= N) { sq[idx] = 0.f; hd[idx] = 1.f; return; }
  const float* Xr = ws_xr + (size_t)b * KSP * NPAD + n;
  float s = 0.f, h0 = b1[0], h1 = b1[1], h2 = b1[2];
  for (int k = 0; k < KS; ++k) {
    float v = Xr[(size_t)k * NPAD];
    s += v * v;
    h0 += v * w1[k];
    h1 += v * w1[KS + k];
    h2 += v * w1[2 * KS + k];
  }
  h0 = fmaxf(h0, 0.f); h1 = fmaxf(h1, 0.f); h2 = fmaxf(h2, 0.f);
  float h = h0 * w2[0] + h1 * w2[1] + h2 * w2[2] + b2[0];
  sq[idx] = s;
  hd[idx] = h * h + 1.f;
}

// ---------------- GEMM1 (symmetric-half): att = (2*XY - sq_n - sq_m) / hd_n ----------------
__global__ __launch_bounds__(256) void nl_gemm1(const float* __restrict__ ws_xr,
                                                const float* __restrict__ sq,
                                                const float* __restrict__ hd,
                                                float* __restrict__ att) {
  int bx = blockIdx.x, by = blockIdx.y;
  if (bx < by) return;  // upper triangle incl. diagonal; mirror writes lower
  __shared__ float As[32][128];
  __shared__ float Bs[32][128];
  int b = blockIdx.z;
  const float* Xb = ws_xr + (size_t)b * KSP * NPAD;
  int row0 = by * 128, col0 = bx * 128;
  int t = threadIdx.x;
  int tr = t >> 4, tc = t & 15;
  float acc[8][8];
#pragma unroll
  for (int i = 0; i < 8; ++i)
#pragma unroll
    for (int j = 0; j < 8; ++j) acc[i][j] = 0.f;

  for (int kt = 0; kt < KSP; kt += 32) {
#pragma unroll
    for (int u = 0; u < 4; ++u) {
      int e = t + u * 256;
      int kk = e >> 5, cc = e & 31;
      float4 va = *(const float4*)(Xb + (size_t)(kt + kk) * NPAD + row0 + cc * 4);
      *(float4*)(&As[kk][cc * 4]) = va;
      float4 vb = *(const float4*)(Xb + (size_t)(kt + kk) * NPAD + col0 + cc * 4);
      *(float4*)(&Bs[kk][cc * 4]) = vb;
    }
    __syncthreads();
#pragma unroll
    for (int kk = 0; kk < 32; ++kk) {
      float a[8], bb[8];
      *(float4*)(&a[0]) = *(const float4*)(&As[kk][tr * 4]);
      *(float4*)(&a[4]) = *(const float4*)(&As[kk][64 + tr * 4]);
      *(float4*)(&bb[0]) = *(const float4*)(&Bs[kk][tc * 4]);
      *(float4*)(&bb[4]) = *(const float4*)(&Bs[kk][64 + tc * 4]);
#pragma unroll
      for (int i = 0; i < 8; ++i)
#pragma unroll
        for (int j = 0; j < 8; ++j) acc[i][j] = fmaf(a[i], bb[j], acc[i][j]);
    }
    __syncthreads();
  }
  int rI[8], cJ[8];
#pragma unroll
  for (int i = 0; i < 4; ++i) { rI[i] = row0 + tr * 4 + i; rI[i + 4] = row0 + 64 + tr * 4 + i; }
#pragma unroll
  for (int j = 0; j < 4; ++j) { cJ[j] = col0 + tc * 4 + j; cJ[j + 4] = col0 + 64 + tc * 4 + j; }
  float sqn[8], hdn[8], sqm[8], hdm[8];
#pragma unroll
  for (int i = 0; i < 8; ++i) { sqn[i] = sq[b * NPAD + rI[i]]; hdn[i] = hd[b * NPAD + rI[i]]; }
#pragma unroll
  for (int j = 0; j < 8; ++j) { sqm[j] = sq[b * NPAD + cJ[j]]; hdm[j] = hd[b * NPAD + cJ[j]]; }
#pragma unroll
  for (int i = 0; i < 8; ++i) {
    float v[8];
    float inv = 1.f / hdn[i];
#pragma unroll
    for (int j = 0; j < 8; ++j) v[j] = (2.f * acc[i][j] - sqn[i] - sqm[j]) * inv;
    float* arow = att + ((size_t)b * NPAD + rI[i]) * NPAD;
    *(float4*)(arow + col0 + tc * 4) = *(float4*)(&v[0]);
    *(float4*)(arow + col0 + 64 + tc * 4) = *(float4*)(&v[4]);
  }
  if (bx != by) {
#pragma unroll
    for (int j = 0; j < 8; ++j) {
      float v[8];
      float inv = 1.f / hdm[j];
#pragma unroll
      for (int i = 0; i < 8; ++i) v[i] = (2.f * acc[i][j] - sqm[j] - sqn[i]) * inv;
      float* arow = att + ((size_t)b * NPAD + cJ[j]) * NPAD;
      *(float4*)(arow + row0 + tr * 4) = *(float4*)(&v[0]);
      *(float4*)(arow + row0 + 64 + tr * 4) = *(float4*)(&v[4]);
    }
  }
}

// ---------------- softmax stats (read-only, single online pass): mx[n], Dinv[n] ----------------
__global__ __launch_bounds__(256) void nl_softmax(const float* __restrict__ att,
                                                  const float* __restrict__ blk,
                                                  float* __restrict__ mxo,
                                                  float* __restrict__ dinv) {
  int n = blockIdx.x, b = blockIdx.y;
  int tid = threadIdx.x;
  const float* row = att + ((size_t)b * NPAD + n) * NPAD;
  const float* bl = blk + b * NPAD;
  float lm = -1e30f, l1 = 0.f, l2 = 0.f;
  for (int m = tid; m < N; m += 256) {
    float v = row[m];
    if (v > lm) { float sc = __expf(lm - v); l1 *= sc; l2 *= sc; lm = v; }
    float e = __expf(v - lm);
    l1 += e; l2 += e * bl[m];
  }
  __shared__ float rm[256], r1[256], r2[256];
  rm[tid] = lm; r1[tid] = l1; r2[tid] = l2;
  __syncthreads();
  for (int s = 128; s > 0; s >>= 1) {
    if (tid < s) {
      float m2 = rm[tid + s];
      if (m2 > rm[tid]) {
        float sc = __expf(rm[tid] - m2);
        r1[tid] = r1[tid] * sc + r1[tid + s];
        r2[tid] = r2[tid] * sc + r2[tid + s];
        rm[tid] = m2;
      } else {
        float sc = __expf(m2 - rm[tid]);
        r1[tid] += r1[tid + s] * sc;
        r2[tid] += r2[tid + s] * sc;
      }
    }
    __syncthreads();
  }
  if (tid == 0) {
    mxo[b * NPAD + n] = rm[0];
    dinv[b * NPAD + n] = 1.f / (r2[0] + 0.001f * r1[0]);
  }
}

// ---------------- GEMM2: out[k,n] += exp(att[n,m]-mx)*blk[m]*Dinv[n]*Xi[k,m]
//                  128n x 160k tile, m-chunk 256, split-13, reg-prefetch pipeline ----------------
__global__ __launch_bounds__(256) void nl_gemm2(const float* __restrict__ att,
                                                const float* __restrict__ ws_xi,
                                                const float* __restrict__ mx,
                                                const float* __restrict__ dinv,
                                                const float* __restrict__ blk,
                                                float* __restrict__ outp0) {
  __shared__ float Ps[32][129];   // [m][n] transposed, odd stride -> conflict-free
  __shared__ float Xs[32][161];   // [m][k] transposed
  __shared__ float mxl[128], dil[128];
  int b = blockIdx.z;
  int n0 = blockIdx.x * 128;
  int m0 = blockIdx.y * MCHUNK;
  const float* attb = att + (size_t)b * NPAD * NPAD;
  const float* Xib = ws_xi + (size_t)b * KSP * NPAD;
  const float* blkb = blk + b * NPAD;
  int t = threadIdx.x;
  if (t < 128) {
    mxl[t] = mx[b * NPAD + n0 + t];
    dil[t] = dinv[b * NPAD + n0 + t];
  }
  int tn = t & 15, tk = t >> 4;
  float acc[8][10];
#pragma unroll
  for (int i = 0; i < 8; ++i)
#pragma unroll
    for (int j = 0; j < 10; ++j) acc[i][j] = 0.f;

  float4 pa[4], px[5];
  // prologue load (iter 0)
#pragma unroll
  for (int u = 0; u < 4; ++u) {
    int e = t + u * 256; int r = e >> 3, c = e & 7;
    pa[u] = *(const float4*)(attb + (size_t)(n0 + r) * NPAD + m0 + c * 4);
  }
#pragma unroll
  for (int u = 0; u < 5; ++u) {
    int e = t + u * 256; int r = e >> 3, c = e & 7;
    px[u] = *(const float4*)(Xib + (size_t)r * NPAD + m0 + c * 4);
  }

  for (int it = 0; it < MCHUNK / 32; ++it) {
    int mt = m0 + it * 32;
    __syncthreads();  // previous compute done (and mxl/dil ready on it=0)
    // store staged regs -> LDS, with softmax transform on the att tile
#pragma unroll
    for (int u = 0; u < 4; ++u) {
      int e = t + u * 256; int r = e >> 3, c = e & 7;
      float4 bl4 = *(const float4*)(blkb + mt + c * 4);
      float mxv = mxl[r], dv = dil[r];
      Ps[c * 4 + 0][r] = __expf(pa[u].x - mxv) * bl4.x * dv;
      Ps[c * 4 + 1][r] = __expf(pa[u].y - mxv) * bl4.y * dv;
      Ps[c * 4 + 2][r] = __expf(pa[u].z - mxv) * bl4.z * dv;
      Ps[c * 4 + 3][r] = __expf(pa[u].w - mxv) * bl4.w * dv;
    }
#pragma unroll
    for (int u = 0; u < 5; ++u) {
      int e = t + u * 256; int r = e >> 3, c = e & 7;
      Xs[c * 4 + 0][r] = px[u].x; Xs[c * 4 + 1][r] = px[u].y;
      Xs[c * 4 + 2][r] = px[u].z; Xs[c * 4 + 3][r] = px[u].w;
    }
    __syncthreads();
    if (it < MCHUNK / 32 - 1) {  // prefetch next tile; latency hides under compute
      int mn = mt + 32;
#pragma unroll
      for (int u = 0; u < 4; ++u) {
        int e = t + u * 256; int r = e >> 3, c = e & 7;
        pa[u] = *(const float4*)(attb + (size_t)(n0 + r) * NPAD + mn + c * 4);
      }
#pragma unroll
      for (int u = 0; u < 5; ++u) {
        int e = t + u * 256; int r = e >> 3, c = e & 7;
        px[u] = *(const float4*)(Xib + (size_t)r * NPAD + mn + c * 4);
      }
    }
#pragma unroll
    for (int mm = 0; mm < 32; ++mm) {
      float a[8], bb[10];
#pragma unroll
      for (int i = 0; i < 8; ++i) a[i] = Ps[mm][tn + 16 * i];
#pragma unroll
      for (int j = 0; j < 10; ++j) bb[j] = Xs[mm][tk + 16 * j];
#pragma unroll
      for (int i = 0; i < 8; ++i)
#pragma unroll
        for (int j = 0; j < 10; ++j) acc[i][j] = fmaf(a[i], bb[j], acc[i][j]);
    }
  }
  float* outp = outp0 + (size_t)b * KSP * NPAD;
#pragma unroll
  for (int i = 0; i < 8; ++i) {
    int n = n0 + tn + 16 * i;
#pragma unroll
    for (int j = 0; j < 10; ++j) {
      int k = tk + 16 * j;
      atomicAdd(outp + (size_t)k * NPAD + n, acc[i][j]);
    }
  }
}

// ---------------- fold (overlap-add adjoint of im2col) + weight divide ----------------
__global__ __launch_bounds__(256) void nl_fold(const float* __restrict__ outA,
                                               float* __restrict__ out) {
  int idx = blockIdx.x * 256 + threadIdx.x;
  if (idx >= B * C * H * W) return;
  int q = idx % W, t = idx / W;
  int p = t % H, t2 = t / H;
  int c = t2 % C, b = t2 / C;
  float s = 0.f;
#pragma unroll
  for (int ky = 0; ky < K; ++ky) {
    int iy = p - ky;
    if (iy < 0 || iy >= NH) continue;
#pragma unroll
    for (int kx = 0; kx < K; ++kx) {
      int jx = q - kx;
      if (jx < 0 || jx >= NW) continue;
      size_t o = ((size_t)(b * KSP + c * 49 + ky * 7 + kx)) * NPAD + iy * NW + jx;
      s += outA[o];
    }
  }
  int cy = min(p, 6) - max(0, p - 56) + 1;
  int cx = min(q, 6) - max(0, q - 56) + 1;
  out[idx] = s / (float)(cy * cx);
}

extern "C" void kernel_launch(void* const* d_in, const int* in_sizes, int n_in,
                              void* d_out, int out_size, void* d_ws, size_t ws_size,
                              hipStream_t stream) {
  const float* x = (const float*)d_in[0];
  const float* y = (const float*)d_in[1];
  const float* w1 = (const float*)d_in[2];
  const float* b1 = (const float*)d_in[3];
  const float* w2 = (const float*)d_in[4];
  const float* b2 = (const float*)d_in[5];
  float* ws = (float*)d_ws;
  float* out = (float*)d_out;

  float* Xr = ws + OFF_XR;
  float* Xi = ws + OFF_XI;
  float* sq = ws + OFF_SQ;
  float* hd = ws + OFF_HD;
  float* blk = ws + OFF_BLK;
  float* Dv = ws + OFF_D;
  float* mx = ws + OFF_MX;
  float* bimg = ws + OFF_BIMG;
  float* att = ws + OFF_ATT;
  float* outA = ws + OFF_OUTA;

  hipMemsetAsync(outA, 0, SZ_X * sizeof(float), stream);

  nl_block<<<(B * H * W + 255) / 256, 256, 0, stream>>>(x, y, bimg);
  nl_im2col<<<(int)((2 * SZ_X + 255) / 256), 256, 0, stream>>>(x, y, ws);
  nl_blkp<<<(B * NPAD + 255) / 256, 256, 0, stream>>>(bimg, blk);
  nl_sqh<<<(B * NPAD + 255) / 256, 256, 0, stream>>>(Xr, w1, b1, w2, b2, sq, hd, Dv, mx);
  nl_gemm1<<<dim3(NPAD / 128, NPAD / 128, B), 256, 0, stream>>>(Xr, sq, hd, att);
  nl_softmax<<<dim3(N, B), 256, 0, stream>>>(att, blk, mx, Dv);
  nl_gemm2<<<dim3(NPAD / 128, SPLITS, B), 256, 0, stream>>>(att, Xi, mx, Dv, blk, outA);
  nl_fold<<<(B * C * H * W + 255) / 256, 256, 0, stream>>>(outA, out);
}